// Round 5
// baseline (191.337 us; speedup 1.0000x reference)
//
#include <hip/hip_runtime.h>
#include <hip/hip_bf16.h>

typedef __bf16 bf16;
typedef __bf16 bf16x8 __attribute__((ext_vector_type(8)));
typedef __bf16 bf16x4 __attribute__((ext_vector_type(4)));
typedef float f32x4 __attribute__((ext_vector_type(4)));

static constexpr int S = 2048, U = 1024, NB = 2, NH = 16, HD = 64;
static constexpr float NEGC = -4294967295.0f;

__device__ __forceinline__ void gload_lds16(const void* g, void* l) {
  __builtin_amdgcn_global_load_lds((const __attribute__((address_space(1))) void*)g,
                                   (__attribute__((address_space(3))) void*)l, 16, 0, 0);
}

// ---------------- fused fp32->bf16 conversion (A + W) + padding masks ----------------
// one block per row (128 threads, 8 elems/thread)
__global__ __launch_bounds__(128) void conv_kernel(
    const float* __restrict__ queries, const float* __restrict__ keys, const float* __restrict__ values,
    const float* __restrict__ Wq, const float* __restrict__ Wk, const float* __restrict__ Wv,
    bf16* __restrict__ Aq, bf16* __restrict__ Ak, bf16* __restrict__ Av,
    bf16* __restrict__ Wb, float* __restrict__ masks)
{
  const int idx = blockIdx.x;               // 0..15359
  const int tid = threadIdx.x;
  const float* src;
  bf16* dst;
  if (idx < 4096)       { src = queries + (size_t)idx * U;          dst = Aq + (size_t)idx * U; }
  else if (idx < 8192)  { src = keys + (size_t)(idx - 4096) * U;    dst = Ak + (size_t)(idx - 4096) * U; }
  else if (idx < 12288) { src = values + (size_t)(idx - 8192) * U;  dst = Av + (size_t)(idx - 8192) * U; }
  else {
    int r2 = idx - 12288;
    int zz = r2 >> 10, row = r2 & 1023;
    src = (zz == 0 ? Wq : (zz == 1 ? Wk : Wv)) + (size_t)row * U;
    dst = Wb + ((size_t)zz << 20) + (size_t)row * U;
  }
  float4 f0 = *reinterpret_cast<const float4*>(src + tid * 8);
  float4 f1 = *reinterpret_cast<const float4*>(src + tid * 8 + 4);
  bf16x8 o;
  o[0]=(bf16)f0.x; o[1]=(bf16)f0.y; o[2]=(bf16)f0.z; o[3]=(bf16)f0.w;
  o[4]=(bf16)f1.x; o[5]=(bf16)f1.y; o[6]=(bf16)f1.z; o[7]=(bf16)f1.w;
  *reinterpret_cast<bf16x8*>(dst + tid * 8) = o;

  if (idx < 8192) {   // query/key padding masks: sign(|row sum|)
    float s = f0.x + f0.y + f0.z + f0.w + f1.x + f1.y + f1.z + f1.w;
#pragma unroll
    for (int off = 1; off < 64; off <<= 1) s += __shfl_xor(s, off, 64);
    __shared__ float ss[2];
    if ((tid & 63) == 0) ss[tid >> 6] = s;
    __syncthreads();
    if (tid == 0) masks[idx] = ((ss[0] + ss[1]) != 0.0f) ? 1.0f : 0.0f;
  }
}

// ---------------- QKV projection: O = relu(A @ W^T + b), all-bf16 m97 structure ----------------
// grid (32 m-tiles, 8 n-tiles, 3 z): bid%8 == m%8 -> A-panel sharers land on one XCD's L2
__global__ __launch_bounds__(256) void proj_kernel(
    const bf16* __restrict__ Aq, const bf16* __restrict__ Ak, const bf16* __restrict__ Av,
    const float* __restrict__ bq, const float* __restrict__ bk, const float* __restrict__ bv,
    const bf16* __restrict__ Wb, bf16* __restrict__ Qb, bf16* __restrict__ Kb, bf16* __restrict__ Vb)
{
  const int z = blockIdx.z;
  const bf16* A     = z == 0 ? Aq : (z == 1 ? Ak : Av);
  const float* bias = z == 0 ? bq : (z == 1 ? bk : bv);
  bf16* O           = z == 0 ? Qb : (z == 1 ? Kb : Vb);
  const bf16* W = Wb + ((size_t)z << 20);

  const int m0 = blockIdx.x * 128;
  const int n0 = blockIdx.y * 128;
  const int tid = threadIdx.x;
  const int lane = tid & 63;
  const int w = tid >> 6;
  const int lg = lane >> 4, li = lane & 15;
  const int wr = w >> 1, wc = w & 1;

  __shared__ bf16 As[8 * 128 * 8];   // [g][m][8], linear, DMA-staged (16 KB)
  __shared__ bf16 Ws[8 * 128 * 8];   // [g][n][8], linear, DMA-staged (16 KB)

  f32x4 acc[4][4] = {};

  for (int kt = 0; kt < 16; ++kt) {
    const int k0 = kt * 64;
#pragma unroll
    for (int j = 0; j < 4; ++j) {
      int c = j * 256 + w * 64 + lane;           // wave-contiguous
      int g = c >> 7, r = c & 127;
      char* dstA = (char*)As + (size_t)(j * 256 + w * 64) * 16;
      char* dstW = (char*)Ws + (size_t)(j * 256 + w * 64) * 16;
      gload_lds16(A + (size_t)(m0 + r) * U + k0 + g * 8, dstA);
      gload_lds16(W + (size_t)(n0 + r) * U + k0 + g * 8, dstW);
    }
    __syncthreads();
#pragma unroll
    for (int s = 0; s < 2; ++s) {
      const int g = s * 4 + lg;
      bf16x8 af[4], wf[4];
#pragma unroll
      for (int mi = 0; mi < 4; ++mi)
        af[mi] = *reinterpret_cast<const bf16x8*>(As + (size_t)(g * 128 + wr * 64 + mi * 16 + li) * 8);
#pragma unroll
      for (int ni = 0; ni < 4; ++ni)
        wf[ni] = *reinterpret_cast<const bf16x8*>(Ws + (size_t)(g * 128 + wc * 64 + ni * 16 + li) * 8);
#pragma unroll
      for (int mi = 0; mi < 4; ++mi)
#pragma unroll
        for (int ni = 0; ni < 4; ++ni)
          acc[mi][ni] = __builtin_amdgcn_mfma_f32_16x16x32_bf16(af[mi], wf[ni], acc[mi][ni], 0, 0, 0);
    }
    __syncthreads();
  }

  // epilogue: bias + relu + bf16 store
#pragma unroll
  for (int ni = 0; ni < 4; ++ni) {
    int col = n0 + wc * 64 + ni * 16 + li;
    float bv_ = bias[col];
#pragma unroll
    for (int mi = 0; mi < 4; ++mi) {
#pragma unroll
      for (int r = 0; r < 4; ++r) {
        int row = m0 + wr * 64 + mi * 16 + lg * 4 + r;
        float v = acc[mi][ni][r] + bv_;
        O[(size_t)row * U + col] = (bf16)(v > 0.f ? v : 0.f);
      }
    }
  }
}

// ---------------- V transpose per head: Vt[hb][d][s] ----------------
__global__ __launch_bounds__(256) void transv_kernel(const bf16* __restrict__ Vb, bf16* __restrict__ Vt)
{
  const int hb = blockIdx.y;            // h*2+b
  const int h = hb >> 1, b = hb & 1;
  const int s0 = blockIdx.x * 64;
  const int tid = threadIdx.x;
  __shared__ bf16 T[64 * 64];
  char* TB = (char*)T;
#pragma unroll
  for (int j = 0; j < 2; ++j) {
    int c = j * 256 + tid;
    int dg = c & 7, s = c >> 3;
    bf16x8 v = *reinterpret_cast<const bf16x8*>(Vb + (size_t)(b * S + s0 + s) * U + h * 64 + dg * 8);
#pragma unroll
    for (int i = 0; i < 8; ++i) {
      int d = dg * 8 + i;
      int byteoff = (d * 128 + s * 2) ^ ((((d & 7) ^ (d >> 3)) & 7) << 4);
      *reinterpret_cast<bf16*>(TB + byteoff) = v[i];
    }
  }
  __syncthreads();
#pragma unroll
  for (int j = 0; j < 2; ++j) {
    int c = j * 256 + tid;
    int sg = c & 7, d = c >> 3;
    int byteoff = (d * 128 + sg * 16) ^ ((((d & 7) ^ (d >> 3)) & 7) << 4);
    bf16x8 v = *reinterpret_cast<const bf16x8*>(TB + byteoff);
    *reinterpret_cast<bf16x8*>(Vt + (size_t)(hb * 64 + d) * S + s0 + sg * 8) = v;
  }
}

// ---------------- causal flash attention: KVBLK=128, dbuf, paired q-tiles (uniform 17 iters/block) ----------------
__global__ __launch_bounds__(256) void flash_kernel(
    const bf16* __restrict__ Qb, const bf16* __restrict__ Kb, const bf16* __restrict__ Vt,
    const float* __restrict__ masks, float* __restrict__ Out)
{
  const int bid = blockIdx.x;          // grid 512
  const int hb = bid & 31;             // bid%8 == hb%8 -> 4 heads per XCD (L2 locality)
  const int j = bid >> 5;              // 0..15 -> q-tile pair {j, 31-j}: always 17 iters total
  const int h = hb >> 1, b = hb & 1;
  const int tid = threadIdx.x;
  const int lane = tid & 63, w = tid >> 6;
  const int lg = lane >> 4, li = lane & 15;
  const float* qmask = masks;
  const float* kmask = masks + 4096;

  __shared__ bf16 Ks[2][8 * 128 * 8];    // [buf][g=d/8][krow=128][8]  16 KB each
  __shared__ bf16 Vs[2][16 * 64 * 8];    // [buf][g2=k/8][d=64][8]     16 KB each
  __shared__ bf16 Ps[4][16 * 16 * 8];    // per wave [kg=16][q=16][8]   4 KB each

  const size_t krow_base = (size_t)b * S;
  const size_t vrow_base = (size_t)hb * 64;

  auto stage = [&](int buf, int k0) {
#pragma unroll
    for (int j2 = 0; j2 < 4; ++j2) {
      int c = j2 * 256 + tid;
      gload_lds16(Kb + (krow_base + k0 + (c & 127)) * U + h * 64 + (c >> 7) * 8,
                  (char*)Ks[buf] + (size_t)c * 16);
      gload_lds16(Vt + (vrow_base + (c & 63)) * S + k0 + (c >> 6) * 8,
                  (char*)Vs[buf] + (size_t)c * 16);
    }
  };

  int cur = 0;
  for (int phase = 0; phase < 2; ++phase) {
    const int qt = phase ? (31 - j) : j;
    const int q0 = qt * 64;
    const int nIter = (qt >> 1) + 1;

    const int qrow = q0 + w * 16 + li;
    const bf16* qptr = Qb + (size_t)(b * S + qrow) * U + h * 64;
    bf16x8 qf0 = *reinterpret_cast<const bf16x8*>(qptr + lg * 8);
    bf16x8 qf1 = *reinterpret_cast<const bf16x8*>(qptr + 32 + lg * 8);

    f32x4 oacc[4] = {};
    float m_run[4], l_run[4];
#pragma unroll
    for (int r = 0; r < 4; ++r) { m_run[r] = -3.0e38f; l_run[r] = 0.0f; }
    const int row_base = q0 + w * 16 + lg * 4;

    stage(cur, 0);
    __syncthreads();

    for (int kv = 0; kv < nIter; ++kv) {
      const int k0 = kv * 128;
      if (kv + 1 < nIter) stage(cur ^ 1, k0 + 128);   // prefetch hides under compute

      const bf16* KsC = Ks[cur];
      const bf16* VsC = Vs[cur];

      // QK^T: 16 q-rows x 128 k-cols per wave
      f32x4 sacc[8] = {};
#pragma unroll
      for (int s = 0; s < 2; ++s) {
        bf16x8 qf = s ? qf1 : qf0;
#pragma unroll
        for (int c = 0; c < 8; ++c) {
          bf16x8 kf = *reinterpret_cast<const bf16x8*>(KsC + (size_t)((s * 4 + lg) * 128 + c * 16 + li) * 8);
          sacc[c] = __builtin_amdgcn_mfma_f32_16x16x32_bf16(qf, kf, sacc[c], 0, 0, 0);
        }
      }

      // mask (in place)
#pragma unroll
      for (int c = 0; c < 8; ++c) {
        int kcol = k0 + c * 16 + li;
        float km = kmask[b * S + kcol];
#pragma unroll
        for (int r = 0; r < 4; ++r) {
          float v = sacc[c][r] * 0.125f;
          if (km == 0.0f || kcol > row_base + r) v = NEGC;
          sacc[c][r] = v;
        }
      }

      // online softmax over 128 cols
#pragma unroll
      for (int r = 0; r < 4; ++r) {
        float mx = fmaxf(fmaxf(fmaxf(sacc[0][r], sacc[1][r]), fmaxf(sacc[2][r], sacc[3][r])),
                         fmaxf(fmaxf(sacc[4][r], sacc[5][r]), fmaxf(sacc[6][r], sacc[7][r])));
        mx = fmaxf(mx, __shfl_xor(mx, 1, 64));
        mx = fmaxf(mx, __shfl_xor(mx, 2, 64));
        mx = fmaxf(mx, __shfl_xor(mx, 4, 64));
        mx = fmaxf(mx, __shfl_xor(mx, 8, 64));
        float mn = fmaxf(m_run[r], mx);
        float alpha = __expf(m_run[r] - mn);
        m_run[r] = mn;
        float ps = 0.f;
#pragma unroll
        for (int c = 0; c < 8; ++c) {
          float p = __expf(sacc[c][r] - mn);
          sacc[c][r] = p;
          ps += p;
        }
        l_run[r] = l_run[r] * alpha + ps;
#pragma unroll
        for (int c = 0; c < 4; ++c) oacc[c][r] *= alpha;
      }

      // P -> LDS (bf16), per-wave region: [kg][q][8]
      bf16* pw = Ps[w];
#pragma unroll
      for (int c = 0; c < 8; ++c) {
        int kl = c * 16 + li;
        int kg2 = kl >> 3, kk = kl & 7;
#pragma unroll
        for (int r = 0; r < 4; ++r)
          pw[(kg2 * 16 + lg * 4 + r) * 8 + kk] = (bf16)sacc[c][r];
      }
      // PV: K=128 -> 4 k-steps of 32
#pragma unroll
      for (int s4 = 0; s4 < 4; ++s4) {
        bf16x8 pf = *reinterpret_cast<const bf16x8*>(pw + (size_t)((s4 * 4 + lg) * 16 + li) * 8);
#pragma unroll
        for (int c = 0; c < 4; ++c) {
          bf16x8 vf = *reinterpret_cast<const bf16x8*>(VsC + (size_t)((s4 * 4 + lg) * 64 + c * 16 + li) * 8);
          oacc[c] = __builtin_amdgcn_mfma_f32_16x16x32_bf16(pf, vf, oacc[c], 0, 0, 0);
        }
      }
      __syncthreads();   // prefetch DMA drained + all reads of cur done
      cur ^= 1;
    }

    // epilogue: normalize, query-mask, store fp32
#pragma unroll
    for (int r = 0; r < 4; ++r) {
      float ls = l_run[r];
      ls += __shfl_xor(ls, 1, 64);
      ls += __shfl_xor(ls, 2, 64);
      ls += __shfl_xor(ls, 4, 64);
      ls += __shfl_xor(ls, 8, 64);
      float qm = qmask[b * S + row_base + r];
      float sc = qm / ls;
#pragma unroll
      for (int c = 0; c < 4; ++c)
        Out[(size_t)(b * S + row_base + r) * U + h * 64 + c * 16 + li] = oacc[c][r] * sc;
    }
  }
}

// ---------------- residual + LayerNorm (ddof=1), in-place on d_out ----------------
__global__ __launch_bounds__(256) void ln_kernel(float* __restrict__ out, const float* __restrict__ queries,
                                                 const float* __restrict__ gamma, const float* __restrict__ beta)
{
  int row = blockIdx.x;
  const float* q = queries + (size_t)row * U;
  float* o = out + (size_t)row * U;
  int tid = threadIdx.x;
  float x[4];
  float s = 0.f, s2 = 0.f;
#pragma unroll
  for (int i = 0; i < 4; ++i) {
    float v = o[tid + i * 256] + q[tid + i * 256];
    x[i] = v; s += v; s2 += v * v;
  }
#pragma unroll
  for (int off = 1; off < 64; off <<= 1) { s += __shfl_xor(s, off, 64); s2 += __shfl_xor(s2, off, 64); }
  __shared__ float ss[4], ssq[4];
  int w = tid >> 6;
  if ((tid & 63) == 0) { ss[w] = s; ssq[w] = s2; }
  __syncthreads();
  s = ss[0] + ss[1] + ss[2] + ss[3];
  s2 = ssq[0] + ssq[1] + ssq[2] + ssq[3];
  float mean = s * (1.0f / 1024.0f);
  float var = (s2 - 1024.0f * mean * mean) * (1.0f / 1023.0f);
  var = fmaxf(var, 0.f);
  float inv = 1.0f / (sqrtf(var) + 1e-8f);
#pragma unroll
  for (int i = 0; i < 4; ++i) {
    int c = tid + i * 256;
    o[c] = gamma[c] * (x[i] - mean) * inv + beta[c];
  }
}

extern "C" void kernel_launch(void* const* d_in, const int* in_sizes, int n_in,
                              void* d_out, int out_size, void* d_ws, size_t ws_size,
                              hipStream_t stream) {
  const float* queries = (const float*)d_in[0];
  const float* keys    = (const float*)d_in[1];
  const float* values  = (const float*)d_in[2];
  const float* Wq = (const float*)d_in[3];
  const float* bq = (const float*)d_in[4];
  const float* Wk = (const float*)d_in[5];
  const float* bk = (const float*)d_in[6];
  const float* Wv = (const float*)d_in[7];
  const float* bv = (const float*)d_in[8];
  const float* gamma = (const float*)d_in[9];
  const float* beta  = (const float*)d_in[10];
  float* out = (float*)d_out;

  char* ws = (char*)d_ws;
  const size_t SZ = (size_t)4096 * 1024 * 2;           // one bf16 [4096][1024] tensor (8 MB)
  bf16* Qb = (bf16*)(ws);
  bf16* Kb = (bf16*)(ws + SZ);
  bf16* Vb = (bf16*)(ws + 2 * SZ);
  bf16* Aq = (bf16*)(ws + 3 * SZ);
  bf16* Ak = (bf16*)(ws + 4 * SZ);
  bf16* Av = (bf16*)(ws + 5 * SZ);
  bf16* Vt = Aq;                                       // alias: Aq dead after proj, Vt written by transv
  bf16* Wb = (bf16*)(ws + 6 * SZ);                     // 3 x [1024][1024] bf16 (6 MB)
  float* masks = (float*)(ws + 6 * SZ + 3 * 2097152);  // qmask[4096], kmask[4096]

  conv_kernel<<<15360, 128, 0, stream>>>(queries, keys, values, Wq, Wk, Wv, Aq, Ak, Av, Wb, masks);
  proj_kernel<<<dim3(32, 8, 3), 256, 0, stream>>>(Aq, Ak, Av, bq, bk, bv, Wb, Qb, Kb, Vb);
  transv_kernel<<<dim3(32, 32), 256, 0, stream>>>(Vb, Vt);
  flash_kernel<<<512, 256, 0, stream>>>(Qb, Kb, Vt, masks, out);
  ln_kernel<<<4096, 256, 0, stream>>>(out, queries, gamma, beta);
}

// Round 6
// 186.020 us; speedup vs baseline: 1.0286x; 1.0286x over previous
//
#include <hip/hip_runtime.h>
#include <hip/hip_bf16.h>

typedef __bf16 bf16;
typedef __bf16 bf16x8 __attribute__((ext_vector_type(8)));
typedef __bf16 bf16x4 __attribute__((ext_vector_type(4)));
typedef float f32x4 __attribute__((ext_vector_type(4)));

static constexpr int S = 2048, U = 1024, NB = 2, NH = 16, HD = 64;
static constexpr float NEGC = -4294967295.0f;

__device__ __forceinline__ void gload_lds16(const void* g, void* l) {
  __builtin_amdgcn_global_load_lds((const __attribute__((address_space(1))) void*)g,
                                   (__attribute__((address_space(3))) void*)l, 16, 0, 0);
}

// ---------------- fused fp32->bf16 conversion (A + W) + padding masks ----------------
// one block per row (128 threads, 8 elems/thread)
// masks[0..4095]   = qmask (0/1)
// masks[4096..8191]= key additive mask (0 or NEGC)
__global__ __launch_bounds__(128) void conv_kernel(
    const float* __restrict__ queries, const float* __restrict__ keys, const float* __restrict__ values,
    const float* __restrict__ Wq, const float* __restrict__ Wk, const float* __restrict__ Wv,
    bf16* __restrict__ Aq, bf16* __restrict__ Ak, bf16* __restrict__ Av,
    bf16* __restrict__ Wb, float* __restrict__ masks)
{
  const int idx = blockIdx.x;               // 0..15359
  const int tid = threadIdx.x;
  const float* src;
  bf16* dst;
  if (idx < 4096)       { src = queries + (size_t)idx * U;          dst = Aq + (size_t)idx * U; }
  else if (idx < 8192)  { src = keys + (size_t)(idx - 4096) * U;    dst = Ak + (size_t)(idx - 4096) * U; }
  else if (idx < 12288) { src = values + (size_t)(idx - 8192) * U;  dst = Av + (size_t)(idx - 8192) * U; }
  else {
    int r2 = idx - 12288;
    int zz = r2 >> 10, row = r2 & 1023;
    src = (zz == 0 ? Wq : (zz == 1 ? Wk : Wv)) + (size_t)row * U;
    dst = Wb + ((size_t)zz << 20) + (size_t)row * U;
  }
  float4 f0 = *reinterpret_cast<const float4*>(src + tid * 8);
  float4 f1 = *reinterpret_cast<const float4*>(src + tid * 8 + 4);
  bf16x8 o;
  o[0]=(bf16)f0.x; o[1]=(bf16)f0.y; o[2]=(bf16)f0.z; o[3]=(bf16)f0.w;
  o[4]=(bf16)f1.x; o[5]=(bf16)f1.y; o[6]=(bf16)f1.z; o[7]=(bf16)f1.w;
  *reinterpret_cast<bf16x8*>(dst + tid * 8) = o;

  if (idx < 8192) {   // padding masks from row sums
    float s = f0.x + f0.y + f0.z + f0.w + f1.x + f1.y + f1.z + f1.w;
#pragma unroll
    for (int off = 1; off < 64; off <<= 1) s += __shfl_xor(s, off, 64);
    __shared__ float ss[2];
    if ((tid & 63) == 0) ss[tid >> 6] = s;
    __syncthreads();
    if (tid == 0) {
      bool nz = (ss[0] + ss[1]) != 0.0f;
      masks[idx] = (idx < 4096) ? (nz ? 1.0f : 0.0f)     // qmask multiplicative
                                : (nz ? 0.0f : NEGC);    // kmask additive
    }
  }
}

// ---------------- QKV projection: O = relu(A @ W^T + b) * sc, all-bf16 m97 structure ----------------
// Q gets sc=0.125 (1/sqrt(d) folded in); grid (32 m, 8 n, 3 z): bid%8==m%8 -> A-panel sharers on one XCD
__global__ __launch_bounds__(256) void proj_kernel(
    const bf16* __restrict__ Aq, const bf16* __restrict__ Ak, const bf16* __restrict__ Av,
    const float* __restrict__ bq, const float* __restrict__ bk, const float* __restrict__ bv,
    const bf16* __restrict__ Wb, bf16* __restrict__ Qb, bf16* __restrict__ Kb, bf16* __restrict__ Vb)
{
  const int z = blockIdx.z;
  const bf16* A     = z == 0 ? Aq : (z == 1 ? Ak : Av);
  const float* bias = z == 0 ? bq : (z == 1 ? bk : bv);
  bf16* O           = z == 0 ? Qb : (z == 1 ? Kb : Vb);
  const float sc    = z == 0 ? 0.125f : 1.0f;
  const bf16* W = Wb + ((size_t)z << 20);

  const int m0 = blockIdx.x * 128;
  const int n0 = blockIdx.y * 128;
  const int tid = threadIdx.x;
  const int lane = tid & 63;
  const int w = tid >> 6;
  const int lg = lane >> 4, li = lane & 15;
  const int wr = w >> 1, wc = w & 1;

  __shared__ bf16 As[8 * 128 * 8];   // [g][m][8], linear, DMA-staged (16 KB)
  __shared__ bf16 Ws[8 * 128 * 8];   // [g][n][8], linear, DMA-staged (16 KB)

  f32x4 acc[4][4] = {};

  for (int kt = 0; kt < 16; ++kt) {
    const int k0 = kt * 64;
#pragma unroll
    for (int j = 0; j < 4; ++j) {
      int c = j * 256 + w * 64 + lane;           // wave-contiguous
      int g = c >> 7, r = c & 127;
      char* dstA = (char*)As + (size_t)(j * 256 + w * 64) * 16;
      char* dstW = (char*)Ws + (size_t)(j * 256 + w * 64) * 16;
      gload_lds16(A + (size_t)(m0 + r) * U + k0 + g * 8, dstA);
      gload_lds16(W + (size_t)(n0 + r) * U + k0 + g * 8, dstW);
    }
    __syncthreads();
#pragma unroll
    for (int s = 0; s < 2; ++s) {
      const int g = s * 4 + lg;
      bf16x8 af[4], wf[4];
#pragma unroll
      for (int mi = 0; mi < 4; ++mi)
        af[mi] = *reinterpret_cast<const bf16x8*>(As + (size_t)(g * 128 + wr * 64 + mi * 16 + li) * 8);
#pragma unroll
      for (int ni = 0; ni < 4; ++ni)
        wf[ni] = *reinterpret_cast<const bf16x8*>(Ws + (size_t)(g * 128 + wc * 64 + ni * 16 + li) * 8);
#pragma unroll
      for (int mi = 0; mi < 4; ++mi)
#pragma unroll
        for (int ni = 0; ni < 4; ++ni)
          acc[mi][ni] = __builtin_amdgcn_mfma_f32_16x16x32_bf16(af[mi], wf[ni], acc[mi][ni], 0, 0, 0);
    }
    __syncthreads();
  }

  // epilogue: bias + relu + scale + bf16 store
#pragma unroll
  for (int ni = 0; ni < 4; ++ni) {
    int col = n0 + wc * 64 + ni * 16 + li;
    float bv_ = bias[col];
#pragma unroll
    for (int mi = 0; mi < 4; ++mi) {
#pragma unroll
      for (int r = 0; r < 4; ++r) {
        int row = m0 + wr * 64 + mi * 16 + lg * 4 + r;
        float v = acc[mi][ni][r] + bv_;
        v = (v > 0.f ? v : 0.f) * sc;
        O[(size_t)row * U + col] = (bf16)v;
      }
    }
  }
}

// ---------------- V transpose per head: Vt[hb][d][s] ----------------
__global__ __launch_bounds__(256) void transv_kernel(const bf16* __restrict__ Vb, bf16* __restrict__ Vt)
{
  const int hb = blockIdx.y;            // h*2+b
  const int h = hb >> 1, b = hb & 1;
  const int s0 = blockIdx.x * 64;
  const int tid = threadIdx.x;
  __shared__ bf16 T[64 * 64];
  char* TB = (char*)T;
#pragma unroll
  for (int j = 0; j < 2; ++j) {
    int c = j * 256 + tid;
    int dg = c & 7, s = c >> 3;
    bf16x8 v = *reinterpret_cast<const bf16x8*>(Vb + (size_t)(b * S + s0 + s) * U + h * 64 + dg * 8);
#pragma unroll
    for (int i = 0; i < 8; ++i) {
      int d = dg * 8 + i;
      int byteoff = (d * 128 + s * 2) ^ ((((d & 7) ^ (d >> 3)) & 7) << 4);
      *reinterpret_cast<bf16*>(TB + byteoff) = v[i];
    }
  }
  __syncthreads();
#pragma unroll
  for (int j = 0; j < 2; ++j) {
    int c = j * 256 + tid;
    int sg = c & 7, d = c >> 3;
    int byteoff = (d * 128 + sg * 16) ^ ((((d & 7) ^ (d >> 3)) & 7) << 4);
    bf16x8 v = *reinterpret_cast<const bf16x8*>(TB + byteoff);
    *reinterpret_cast<bf16x8*>(Vt + (size_t)(hb * 64 + d) * S + s0 + sg * 8) = v;
  }
}

// ---------------- causal flash attention: KVBLK=64, dbuf, exact per-CU balance + XCD locality ----------------
__global__ __launch_bounds__(256) void flash_kernel(
    const bf16* __restrict__ Qb, const bf16* __restrict__ Kb, const bf16* __restrict__ Vt,
    const float* __restrict__ masks, float* __restrict__ Out)
{
  // same-CU sets {bid,+256,+512,+768}: qt in {base,15-base,16+base,31-base} -> sum 62 (66 iters) on every CU.
  // hb = bid&31 -> bid%8 == hb%8: each XCD serves 4 heads (K/V L2-resident).
  const int bid = blockIdx.x;          // grid 1024
  const int hb = bid & 31;
  const int base = (bid >> 5) & 7;
  const int kk4 = bid >> 8;            // 0..3
  const int qt = (kk4 == 0) ? base : (kk4 == 1) ? 15 - base : (kk4 == 2) ? 16 + base : 31 - base;
  const int h = hb >> 1, b = hb & 1;
  const int q0 = qt * 64;
  const int tid = threadIdx.x;
  const int lane = tid & 63, w = tid >> 6;
  const int lg = lane >> 4, li = lane & 15;
  const float* qmask = masks;
  const float* kmask = masks + 4096;   // additive: 0 or NEGC

  __shared__ bf16 Ks[2][8 * 64 * 8];   // [buf][g][k][8], 8 KB each
  __shared__ bf16 Vs[2][8 * 64 * 8];   // [buf][g][d][8] (from Vt: V[k][d] k-contig)
  __shared__ bf16 Ps[4][8 * 16 * 8];   // per wave [kg][q][8]

  const int qrow = q0 + w * 16 + li;
  const bf16* qptr = Qb + (size_t)(b * S + qrow) * U + h * 64;
  bf16x8 qf0 = *reinterpret_cast<const bf16x8*>(qptr + lg * 8);
  bf16x8 qf1 = *reinterpret_cast<const bf16x8*>(qptr + 32 + lg * 8);

  f32x4 oacc[4] = {};
  float m_run[4], l_run[4];
#pragma unroll
  for (int r = 0; r < 4; ++r) { m_run[r] = -3.0e38f; l_run[r] = 0.0f; }

  const int row_base = q0 + w * 16 + lg * 4;
  const size_t krow_base = (size_t)b * S;
  const size_t vrow_base = (size_t)hb * 64;
  const int g0 = w;         // j=0 group
  const int g1 = 4 + w;     // j=1 group

  // stage tile 0 into buffer 0
  {
    gload_lds16(Kb + (krow_base + lane) * U + h * 64 + g0 * 8, (char*)Ks[0] + (size_t)(g0 * 64) * 16);
    gload_lds16(Vt + (vrow_base + lane) * S + g0 * 8,          (char*)Vs[0] + (size_t)(g0 * 64) * 16);
    gload_lds16(Kb + (krow_base + lane) * U + h * 64 + g1 * 8, (char*)Ks[0] + (size_t)(g1 * 64) * 16);
    gload_lds16(Vt + (vrow_base + lane) * S + g1 * 8,          (char*)Vs[0] + (size_t)(g1 * 64) * 16);
  }
  __syncthreads();

  int cur = 0;
  for (int kv = 0; kv <= qt; ++kv) {
    const int k0 = kv * 64;

    // prefetch next K/V tile into the other buffer (latency hides under compute)
    if (kv < qt) {
      const int kn = k0 + 64;
      char* kd = (char*)Ks[cur ^ 1];
      char* vd = (char*)Vs[cur ^ 1];
      gload_lds16(Kb + (krow_base + kn + lane) * U + h * 64 + g0 * 8, kd + (size_t)(g0 * 64) * 16);
      gload_lds16(Vt + (vrow_base + lane) * S + kn + g0 * 8,          vd + (size_t)(g0 * 64) * 16);
      gload_lds16(Kb + (krow_base + kn + lane) * U + h * 64 + g1 * 8, kd + (size_t)(g1 * 64) * 16);
      gload_lds16(Vt + (vrow_base + lane) * S + kn + g1 * 8,          vd + (size_t)(g1 * 64) * 16);
    }

    const bf16* KsC = Ks[cur];
    const bf16* VsC = Vs[cur];

    f32x4 sacc[4] = {};
#pragma unroll
    for (int s = 0; s < 2; ++s) {
      bf16x8 qf = s ? qf1 : qf0;
#pragma unroll
      for (int c = 0; c < 4; ++c) {
        bf16x8 kf = *reinterpret_cast<const bf16x8*>(KsC + (size_t)((s * 4 + lg) * 64 + c * 16 + li) * 8);
        sacc[c] = __builtin_amdgcn_mfma_f32_16x16x32_bf16(qf, kf, sacc[c], 0, 0, 0);
      }
    }

    // masks: additive key mask always; causal cndmask only on the diagonal tile
    float sv[4][4];
    const float* kaddp = kmask + b * S + k0;
#pragma unroll
    for (int c = 0; c < 4; ++c) {
      float ka = kaddp[c * 16 + li];
#pragma unroll
      for (int r = 0; r < 4; ++r) sv[c][r] = sacc[c][r] + ka;
    }
    if (kv == qt) {
#pragma unroll
      for (int c = 0; c < 4; ++c) {
        int kcol = k0 + c * 16 + li;
#pragma unroll
        for (int r = 0; r < 4; ++r) if (kcol > row_base + r) sv[c][r] = NEGC;
      }
    }

#pragma unroll
    for (int r = 0; r < 4; ++r) {
      float mx = fmaxf(fmaxf(sv[0][r], sv[1][r]), fmaxf(sv[2][r], sv[3][r]));
      mx = fmaxf(mx, __shfl_xor(mx, 1, 64));
      mx = fmaxf(mx, __shfl_xor(mx, 2, 64));
      mx = fmaxf(mx, __shfl_xor(mx, 4, 64));
      mx = fmaxf(mx, __shfl_xor(mx, 8, 64));
      float mn = fmaxf(m_run[r], mx);
      float alpha = __expf(m_run[r] - mn);
      m_run[r] = mn;
      float ps = 0.f;
#pragma unroll
      for (int c = 0; c < 4; ++c) {
        float p = __expf(sv[c][r] - mn);
        sv[c][r] = p;
        ps += p;
      }
      l_run[r] = l_run[r] * alpha + ps;
#pragma unroll
      for (int c = 0; c < 4; ++c) oacc[c][r] *= alpha;
    }

    // P -> LDS (bf16), per-wave region
    bf16* pw = Ps[w];
#pragma unroll
    for (int c = 0; c < 4; ++c) {
      int kl = c * 16 + li;
      int kg2 = kl >> 3, kk = kl & 7;
#pragma unroll
      for (int r = 0; r < 4; ++r)
        pw[(kg2 * 16 + lg * 4 + r) * 8 + kk] = (bf16)sv[c][r];
    }
    // PV
#pragma unroll
    for (int s2 = 0; s2 < 2; ++s2) {
      bf16x8 pf = *reinterpret_cast<const bf16x8*>(pw + (size_t)((s2 * 4 + lg) * 16 + li) * 8);
#pragma unroll
      for (int c = 0; c < 4; ++c) {
        bf16x8 vf = *reinterpret_cast<const bf16x8*>(VsC + (size_t)((s2 * 4 + lg) * 64 + c * 16 + li) * 8);
        oacc[c] = __builtin_amdgcn_mfma_f32_16x16x32_bf16(pf, vf, oacc[c], 0, 0, 0);
      }
    }
    __syncthreads();   // next-tile DMA complete (vmcnt drain) + all reads of cur done
    cur ^= 1;
  }

  // epilogue: normalize, query-mask, store merged fp32
#pragma unroll
  for (int r = 0; r < 4; ++r) {
    float ls = l_run[r];
    ls += __shfl_xor(ls, 1, 64);
    ls += __shfl_xor(ls, 2, 64);
    ls += __shfl_xor(ls, 4, 64);
    ls += __shfl_xor(ls, 8, 64);
    float qm = qmask[b * S + row_base + r];
    float sc = qm / ls;
#pragma unroll
    for (int c = 0; c < 4; ++c)
      Out[(size_t)(b * S + row_base + r) * U + h * 64 + c * 16 + li] = oacc[c][r] * sc;
  }
}

// ---------------- residual + LayerNorm (ddof=1), in-place on d_out ----------------
__global__ __launch_bounds__(256) void ln_kernel(float* __restrict__ out, const float* __restrict__ queries,
                                                 const float* __restrict__ gamma, const float* __restrict__ beta)
{
  int row = blockIdx.x;
  const float* q = queries + (size_t)row * U;
  float* o = out + (size_t)row * U;
  int tid = threadIdx.x;
  float x[4];
  float s = 0.f, s2 = 0.f;
#pragma unroll
  for (int i = 0; i < 4; ++i) {
    float v = o[tid + i * 256] + q[tid + i * 256];
    x[i] = v; s += v; s2 += v * v;
  }
#pragma unroll
  for (int off = 1; off < 64; off <<= 1) { s += __shfl_xor(s, off, 64); s2 += __shfl_xor(s2, off, 64); }
  __shared__ float ss[4], ssq[4];
  int w = tid >> 6;
  if ((tid & 63) == 0) { ss[w] = s; ssq[w] = s2; }
  __syncthreads();
  s = ss[0] + ss[1] + ss[2] + ss[3];
  s2 = ssq[0] + ssq[1] + ssq[2] + ssq[3];
  float mean = s * (1.0f / 1024.0f);
  float var = (s2 - 1024.0f * mean * mean) * (1.0f / 1023.0f);
  var = fmaxf(var, 0.f);
  float inv = 1.0f / (sqrtf(var) + 1e-8f);
#pragma unroll
  for (int i = 0; i < 4; ++i) {
    int c = tid + i * 256;
    o[c] = gamma[c] * (x[i] - mean) * inv + beta[c];
  }
}

extern "C" void kernel_launch(void* const* d_in, const int* in_sizes, int n_in,
                              void* d_out, int out_size, void* d_ws, size_t ws_size,
                              hipStream_t stream) {
  const float* queries = (const float*)d_in[0];
  const float* keys    = (const float*)d_in[1];
  const float* values  = (const float*)d_in[2];
  const float* Wq = (const float*)d_in[3];
  const float* bq = (const float*)d_in[4];
  const float* Wk = (const float*)d_in[5];
  const float* bk = (const float*)d_in[6];
  const float* Wv = (const float*)d_in[7];
  const float* bv = (const float*)d_in[8];
  const float* gamma = (const float*)d_in[9];
  const float* beta  = (const float*)d_in[10];
  float* out = (float*)d_out;

  char* ws = (char*)d_ws;
  const size_t SZ = (size_t)4096 * 1024 * 2;           // one bf16 [4096][1024] tensor (8 MB)
  bf16* Qb = (bf16*)(ws);
  bf16* Kb = (bf16*)(ws + SZ);
  bf16* Vb = (bf16*)(ws + 2 * SZ);
  bf16* Aq = (bf16*)(ws + 3 * SZ);
  bf16* Ak = (bf16*)(ws + 4 * SZ);
  bf16* Av = (bf16*)(ws + 5 * SZ);
  bf16* Vt = Aq;                                       // alias: Aq dead after proj, Vt written by transv
  bf16* Wb = (bf16*)(ws + 6 * SZ);                     // 3 x [1024][1024] bf16 (6 MB)
  float* masks = (float*)(ws + 6 * SZ + 3 * 2097152);  // qmask[4096], kmaskAdd[4096]

  conv_kernel<<<15360, 128, 0, stream>>>(queries, keys, values, Wq, Wk, Wv, Aq, Ak, Av, Wb, masks);
  proj_kernel<<<dim3(32, 8, 3), 256, 0, stream>>>(Aq, Ak, Av, bq, bk, bv, Wb, Qb, Kb, Vb);
  transv_kernel<<<dim3(32, 32), 256, 0, stream>>>(Vb, Vt);
  flash_kernel<<<1024, 256, 0, stream>>>(Qb, Kb, Vt, masks, out);
  ln_kernel<<<4096, 256, 0, stream>>>(out, queries, gamma, beta);
}

// Round 7
// 166.487 us; speedup vs baseline: 1.1493x; 1.1173x over previous
//
#include <hip/hip_runtime.h>
#include <hip/hip_bf16.h>

typedef __bf16 bf16;
typedef __bf16 bf16x8 __attribute__((ext_vector_type(8)));
typedef __bf16 bf16x4 __attribute__((ext_vector_type(4)));
typedef float f32x4 __attribute__((ext_vector_type(4)));

static constexpr int S = 2048, U = 1024, NB = 2, NH = 16, HD = 64;
static constexpr float NEGC = -4294967295.0f;

__device__ __forceinline__ void gload_lds16(const void* g, void* l) {
  __builtin_amdgcn_global_load_lds((const __attribute__((address_space(1))) void*)g,
                                   (__attribute__((address_space(3))) void*)l, 16, 0, 0);
}

// ---------------- fused fp32->bf16 conversion (A + W) + padding masks ----------------
// masks[0..4095] = qmask (0/1); masks[4096..8191] = key additive mask (0 or NEGC)
__global__ __launch_bounds__(128) void conv_kernel(
    const float* __restrict__ queries, const float* __restrict__ keys, const float* __restrict__ values,
    const float* __restrict__ Wq, const float* __restrict__ Wk, const float* __restrict__ Wv,
    bf16* __restrict__ Aq, bf16* __restrict__ Ak, bf16* __restrict__ Av,
    bf16* __restrict__ Wb, float* __restrict__ masks)
{
  const int idx = blockIdx.x;               // 0..15359
  const int tid = threadIdx.x;
  const float* src;
  bf16* dst;
  if (idx < 4096)       { src = queries + (size_t)idx * U;          dst = Aq + (size_t)idx * U; }
  else if (idx < 8192)  { src = keys + (size_t)(idx - 4096) * U;    dst = Ak + (size_t)(idx - 4096) * U; }
  else if (idx < 12288) { src = values + (size_t)(idx - 8192) * U;  dst = Av + (size_t)(idx - 8192) * U; }
  else {
    int r2 = idx - 12288;
    int zz = r2 >> 10, row = r2 & 1023;
    src = (zz == 0 ? Wq : (zz == 1 ? Wk : Wv)) + (size_t)row * U;
    dst = Wb + ((size_t)zz << 20) + (size_t)row * U;
  }
  float4 f0 = *reinterpret_cast<const float4*>(src + tid * 8);
  float4 f1 = *reinterpret_cast<const float4*>(src + tid * 8 + 4);
  bf16x8 o;
  o[0]=(bf16)f0.x; o[1]=(bf16)f0.y; o[2]=(bf16)f0.z; o[3]=(bf16)f0.w;
  o[4]=(bf16)f1.x; o[5]=(bf16)f1.y; o[6]=(bf16)f1.z; o[7]=(bf16)f1.w;
  *reinterpret_cast<bf16x8*>(dst + tid * 8) = o;

  if (idx < 8192) {   // padding masks from row sums
    float s = f0.x + f0.y + f0.z + f0.w + f1.x + f1.y + f1.z + f1.w;
#pragma unroll
    for (int off = 1; off < 64; off <<= 1) s += __shfl_xor(s, off, 64);
    __shared__ float ss[2];
    if ((tid & 63) == 0) ss[tid >> 6] = s;
    __syncthreads();
    if (tid == 0) {
      bool nz = (ss[0] + ss[1]) != 0.0f;
      masks[idx] = (idx < 4096) ? (nz ? 1.0f : 0.0f)     // qmask multiplicative
                                : (nz ? 0.0f : NEGC);    // kmask additive
    }
  }
}

// ---------------- QKV projection: O = relu(A @ W^T + b) * sc, all-bf16 m97 structure ----------------
__global__ __launch_bounds__(256) void proj_kernel(
    const bf16* __restrict__ Aq, const bf16* __restrict__ Ak, const bf16* __restrict__ Av,
    const float* __restrict__ bq, const float* __restrict__ bk, const float* __restrict__ bv,
    const bf16* __restrict__ Wb, bf16* __restrict__ Qb, bf16* __restrict__ Kb, bf16* __restrict__ Vb)
{
  const int z = blockIdx.z;
  const bf16* A     = z == 0 ? Aq : (z == 1 ? Ak : Av);
  const float* bias = z == 0 ? bq : (z == 1 ? bk : bv);
  bf16* O           = z == 0 ? Qb : (z == 1 ? Kb : Vb);
  const float sc    = z == 0 ? 0.125f : 1.0f;
  const bf16* W = Wb + ((size_t)z << 20);

  const int m0 = blockIdx.x * 128;
  const int n0 = blockIdx.y * 128;
  const int tid = threadIdx.x;
  const int lane = tid & 63;
  const int w = tid >> 6;
  const int lg = lane >> 4, li = lane & 15;
  const int wr = w >> 1, wc = w & 1;

  __shared__ bf16 As[8 * 128 * 8];   // [g][m][8], linear, DMA-staged (16 KB)
  __shared__ bf16 Ws[8 * 128 * 8];   // [g][n][8], linear, DMA-staged (16 KB)

  f32x4 acc[4][4] = {};

  for (int kt = 0; kt < 16; ++kt) {
    const int k0 = kt * 64;
#pragma unroll
    for (int j = 0; j < 4; ++j) {
      int c = j * 256 + w * 64 + lane;           // wave-contiguous
      int g = c >> 7, r = c & 127;
      char* dstA = (char*)As + (size_t)(j * 256 + w * 64) * 16;
      char* dstW = (char*)Ws + (size_t)(j * 256 + w * 64) * 16;
      gload_lds16(A + (size_t)(m0 + r) * U + k0 + g * 8, dstA);
      gload_lds16(W + (size_t)(n0 + r) * U + k0 + g * 8, dstW);
    }
    __syncthreads();
#pragma unroll
    for (int s = 0; s < 2; ++s) {
      const int g = s * 4 + lg;
      bf16x8 af[4], wf[4];
#pragma unroll
      for (int mi = 0; mi < 4; ++mi)
        af[mi] = *reinterpret_cast<const bf16x8*>(As + (size_t)(g * 128 + wr * 64 + mi * 16 + li) * 8);
#pragma unroll
      for (int ni = 0; ni < 4; ++ni)
        wf[ni] = *reinterpret_cast<const bf16x8*>(Ws + (size_t)(g * 128 + wc * 64 + ni * 16 + li) * 8);
#pragma unroll
      for (int mi = 0; mi < 4; ++mi)
#pragma unroll
        for (int ni = 0; ni < 4; ++ni)
          acc[mi][ni] = __builtin_amdgcn_mfma_f32_16x16x32_bf16(af[mi], wf[ni], acc[mi][ni], 0, 0, 0);
    }
    __syncthreads();
  }

  // epilogue: bias + relu + scale + bf16 store
#pragma unroll
  for (int ni = 0; ni < 4; ++ni) {
    int col = n0 + wc * 64 + ni * 16 + li;
    float bv_ = bias[col];
#pragma unroll
    for (int mi = 0; mi < 4; ++mi) {
#pragma unroll
      for (int r = 0; r < 4; ++r) {
        int row = m0 + wr * 64 + mi * 16 + lg * 4 + r;
        float v = acc[mi][ni][r] + bv_;
        v = (v > 0.f ? v : 0.f) * sc;
        O[(size_t)row * U + col] = (bf16)v;
      }
    }
  }
}

// ---------------- V transpose per head: Vt[hb][d][s] ----------------
__global__ __launch_bounds__(256) void transv_kernel(const bf16* __restrict__ Vb, bf16* __restrict__ Vt)
{
  const int hb = blockIdx.y;            // h*2+b
  const int h = hb >> 1, b = hb & 1;
  const int s0 = blockIdx.x * 64;
  const int tid = threadIdx.x;
  __shared__ bf16 T[64 * 64];
  char* TB = (char*)T;
#pragma unroll
  for (int j = 0; j < 2; ++j) {
    int c = j * 256 + tid;
    int dg = c & 7, s = c >> 3;
    bf16x8 v = *reinterpret_cast<const bf16x8*>(Vb + (size_t)(b * S + s0 + s) * U + h * 64 + dg * 8);
#pragma unroll
    for (int i = 0; i < 8; ++i) {
      int d = dg * 8 + i;
      int byteoff = (d * 128 + s * 2) ^ ((((d & 7) ^ (d >> 3)) & 7) << 4);
      *reinterpret_cast<bf16*>(TB + byteoff) = v[i];
    }
  }
  __syncthreads();
#pragma unroll
  for (int j = 0; j < 2; ++j) {
    int c = j * 256 + tid;
    int sg = c & 7, d = c >> 3;
    int byteoff = (d * 128 + sg * 16) ^ ((((d & 7) ^ (d >> 3)) & 7) << 4);
    bf16x8 v = *reinterpret_cast<const bf16x8*>(TB + byteoff);
    *reinterpret_cast<bf16x8*>(Vt + (size_t)(hb * 64 + d) * S + s0 + sg * 8) = v;
  }
}

// ---------------- causal flash attention: QBLK=128 (8 waves), KVBLK=64, dbuf ----------------
// grid 512, 512 threads. hb=bid&31 (XCD locality); t=bid>>5, qt2 = t<8 ? t : 23-t
// -> same-CU pair {t, t+8} iters = (2t+2)+(2(15-t)+2) = 34, uniform on every CU.
__global__ __launch_bounds__(512) void flash_kernel(
    const bf16* __restrict__ Qb, const bf16* __restrict__ Kb, const bf16* __restrict__ Vt,
    const float* __restrict__ masks, float* __restrict__ Out)
{
  const int bid = blockIdx.x;          // grid 512
  const int hb = bid & 31;
  const int t = bid >> 5;              // 0..15
  const int qt2 = (t < 8) ? t : 23 - t;
  const int h = hb >> 1, b = hb & 1;
  const int q0 = qt2 * 128;
  const int nIter = 2 * qt2 + 2;
  const int tid = threadIdx.x;
  const int lane = tid & 63, w = tid >> 6;   // w 0..7
  const int lg = lane >> 4, li = lane & 15;
  const float* qmask = masks;
  const float* kmask = masks + 4096;   // additive: 0 or NEGC

  __shared__ bf16 Ks[2][8 * 64 * 8];   // [buf][g=d/8][k=64][8], 8 KB each
  __shared__ bf16 Vs[2][8 * 64 * 8];   // [buf][g2=k/8][d=64][8], 8 KB each
  __shared__ bf16 Ps[8][8 * 16 * 8];   // per wave [kg][q][8], 2 KB each

  const int qrow = q0 + w * 16 + li;
  const bf16* qptr = Qb + (size_t)(b * S + qrow) * U + h * 64;
  bf16x8 qf0 = *reinterpret_cast<const bf16x8*>(qptr + lg * 8);
  bf16x8 qf1 = *reinterpret_cast<const bf16x8*>(qptr + 32 + lg * 8);

  f32x4 oacc[4] = {};
  float m_run[4], l_run[4];
#pragma unroll
  for (int r = 0; r < 4; ++r) { m_run[r] = -3.0e38f; l_run[r] = 0.0f; }

  const int row_base = q0 + w * 16 + lg * 4;
  const size_t krow_base = (size_t)b * S;
  const size_t vrow_base = (size_t)hb * 64;
  const int gK = tid >> 6, rK = tid & 63;    // 512 threads -> one 16B K chunk + one 16B V chunk each

  auto stage = [&](int buf, int k0) {
    gload_lds16(Kb + (krow_base + k0 + rK) * U + h * 64 + gK * 8, (char*)Ks[buf] + (size_t)tid * 16);
    gload_lds16(Vt + (vrow_base + rK) * S + k0 + gK * 8,          (char*)Vs[buf] + (size_t)tid * 16);
  };

  stage(0, 0);
  __syncthreads();

  int cur = 0;
  for (int kv = 0; kv < nIter; ++kv) {
    const int k0 = kv * 64;
    if (kv + 1 < nIter) stage(cur ^ 1, k0 + 64);   // prefetch hides under compute

    const bf16* KsC = Ks[cur];
    const bf16* VsC = Vs[cur];

    f32x4 sacc[4] = {};
    __builtin_amdgcn_s_setprio(1);
#pragma unroll
    for (int s = 0; s < 2; ++s) {
      bf16x8 qf = s ? qf1 : qf0;
#pragma unroll
      for (int c = 0; c < 4; ++c) {
        bf16x8 kf = *reinterpret_cast<const bf16x8*>(KsC + (size_t)((s * 4 + lg) * 64 + c * 16 + li) * 8);
        sacc[c] = __builtin_amdgcn_mfma_f32_16x16x32_bf16(qf, kf, sacc[c], 0, 0, 0);
      }
    }
    __builtin_amdgcn_s_setprio(0);

    // masks: additive key mask always; causal cndmask on the last two tiles only
    float sv[4][4];
    const float* kaddp = kmask + b * S + k0;
#pragma unroll
    for (int c = 0; c < 4; ++c) {
      float ka = kaddp[c * 16 + li];
#pragma unroll
      for (int r = 0; r < 4; ++r) sv[c][r] = sacc[c][r] + ka;
    }
    if (kv >= 2 * qt2) {
#pragma unroll
      for (int c = 0; c < 4; ++c) {
        int kcol = k0 + c * 16 + li;
#pragma unroll
        for (int r = 0; r < 4; ++r) if (kcol > row_base + r) sv[c][r] = NEGC;
      }
    }

#pragma unroll
    for (int r = 0; r < 4; ++r) {
      float mx = fmaxf(fmaxf(sv[0][r], sv[1][r]), fmaxf(sv[2][r], sv[3][r]));
      mx = fmaxf(mx, __shfl_xor(mx, 1, 64));
      mx = fmaxf(mx, __shfl_xor(mx, 2, 64));
      mx = fmaxf(mx, __shfl_xor(mx, 4, 64));
      mx = fmaxf(mx, __shfl_xor(mx, 8, 64));
      float mn = fmaxf(m_run[r], mx);
      float alpha = __expf(m_run[r] - mn);
      m_run[r] = mn;
      float ps = 0.f;
#pragma unroll
      for (int c = 0; c < 4; ++c) {
        float p = __expf(sv[c][r] - mn);
        sv[c][r] = p;
        ps += p;
      }
      l_run[r] = l_run[r] * alpha + ps;
#pragma unroll
      for (int c = 0; c < 4; ++c) oacc[c][r] *= alpha;
    }

    // P -> LDS (bf16), per-wave region
    bf16* pw = Ps[w];
#pragma unroll
    for (int c = 0; c < 4; ++c) {
      int kl = c * 16 + li;
      int kg2 = kl >> 3, kk = kl & 7;
#pragma unroll
      for (int r = 0; r < 4; ++r)
        pw[(kg2 * 16 + lg * 4 + r) * 8 + kk] = (bf16)sv[c][r];
    }
    // PV
    __builtin_amdgcn_s_setprio(1);
#pragma unroll
    for (int s2 = 0; s2 < 2; ++s2) {
      bf16x8 pf = *reinterpret_cast<const bf16x8*>(pw + (size_t)((s2 * 4 + lg) * 16 + li) * 8);
#pragma unroll
      for (int c = 0; c < 4; ++c) {
        bf16x8 vf = *reinterpret_cast<const bf16x8*>(VsC + (size_t)((s2 * 4 + lg) * 64 + c * 16 + li) * 8);
        oacc[c] = __builtin_amdgcn_mfma_f32_16x16x32_bf16(pf, vf, oacc[c], 0, 0, 0);
      }
    }
    __builtin_amdgcn_s_setprio(0);
    __syncthreads();   // next-tile DMA complete (vmcnt drain) + all reads of cur done
    cur ^= 1;
  }

  // epilogue: normalize, query-mask, store merged fp32
#pragma unroll
  for (int r = 0; r < 4; ++r) {
    float ls = l_run[r];
    ls += __shfl_xor(ls, 1, 64);
    ls += __shfl_xor(ls, 2, 64);
    ls += __shfl_xor(ls, 4, 64);
    ls += __shfl_xor(ls, 8, 64);
    float qm = qmask[b * S + row_base + r];
    float sc = qm / ls;
#pragma unroll
    for (int c = 0; c < 4; ++c)
      Out[(size_t)(b * S + row_base + r) * U + h * 64 + c * 16 + li] = oacc[c][r] * sc;
  }
}

// ---------------- residual + LayerNorm (ddof=1), in-place on d_out ----------------
__global__ __launch_bounds__(256) void ln_kernel(float* __restrict__ out, const float* __restrict__ queries,
                                                 const float* __restrict__ gamma, const float* __restrict__ beta)
{
  int row = blockIdx.x;
  const float* q = queries + (size_t)row * U;
  float* o = out + (size_t)row * U;
  int tid = threadIdx.x;
  float x[4];
  float s = 0.f, s2 = 0.f;
#pragma unroll
  for (int i = 0; i < 4; ++i) {
    float v = o[tid + i * 256] + q[tid + i * 256];
    x[i] = v; s += v; s2 += v * v;
  }
#pragma unroll
  for (int off = 1; off < 64; off <<= 1) { s += __shfl_xor(s, off, 64); s2 += __shfl_xor(s2, off, 64); }
  __shared__ float ss[4], ssq[4];
  int w = tid >> 6;
  if ((tid & 63) == 0) { ss[w] = s; ssq[w] = s2; }
  __syncthreads();
  s = ss[0] + ss[1] + ss[2] + ss[3];
  s2 = ssq[0] + ssq[1] + ssq[2] + ssq[3];
  float mean = s * (1.0f / 1024.0f);
  float var = (s2 - 1024.0f * mean * mean) * (1.0f / 1023.0f);
  var = fmaxf(var, 0.f);
  float inv = 1.0f / (sqrtf(var) + 1e-8f);
#pragma unroll
  for (int i = 0; i < 4; ++i) {
    int c = tid + i * 256;
    o[c] = gamma[c] * (x[i] - mean) * inv + beta[c];
  }
}

extern "C" void kernel_launch(void* const* d_in, const int* in_sizes, int n_in,
                              void* d_out, int out_size, void* d_ws, size_t ws_size,
                              hipStream_t stream) {
  const float* queries = (const float*)d_in[0];
  const float* keys    = (const float*)d_in[1];
  const float* values  = (const float*)d_in[2];
  const float* Wq = (const float*)d_in[3];
  const float* bq = (const float*)d_in[4];
  const float* Wk = (const float*)d_in[5];
  const float* bk = (const float*)d_in[6];
  const float* Wv = (const float*)d_in[7];
  const float* bv = (const float*)d_in[8];
  const float* gamma = (const float*)d_in[9];
  const float* beta  = (const float*)d_in[10];
  float* out = (float*)d_out;

  char* ws = (char*)d_ws;
  const size_t SZ = (size_t)4096 * 1024 * 2;           // one bf16 [4096][1024] tensor (8 MB)
  bf16* Qb = (bf16*)(ws);
  bf16* Kb = (bf16*)(ws + SZ);
  bf16* Vb = (bf16*)(ws + 2 * SZ);
  bf16* Aq = (bf16*)(ws + 3 * SZ);
  bf16* Ak = (bf16*)(ws + 4 * SZ);
  bf16* Av = (bf16*)(ws + 5 * SZ);
  bf16* Vt = Aq;                                       // alias: Aq dead after proj, Vt written by transv
  bf16* Wb = (bf16*)(ws + 6 * SZ);                     // 3 x [1024][1024] bf16 (6 MB)
  float* masks = (float*)(ws + 6 * SZ + 3 * 2097152);  // qmask[4096], kmaskAdd[4096]

  conv_kernel<<<15360, 128, 0, stream>>>(queries, keys, values, Wq, Wk, Wv, Aq, Ak, Av, Wb, masks);
  proj_kernel<<<dim3(32, 8, 3), 256, 0, stream>>>(Aq, Ak, Av, bq, bk, bv, Wb, Qb, Kb, Vb);
  transv_kernel<<<dim3(32, 32), 256, 0, stream>>>(Vb, Vt);
  flash_kernel<<<512, 512, 0, stream>>>(Qb, Kb, Vt, masks, out);
  ln_kernel<<<4096, 256, 0, stream>>>(out, queries, gamma, beta);
}